// Round 5
// baseline (18572.861 us; speedup 1.0000x reference)
//
#include <hip/hip_runtime.h>
#include <hip/hip_bf16.h>

typedef float f32x4 __attribute__((ext_vector_type(4)));
typedef __bf16 bf16x8 __attribute__((ext_vector_type(8)));
typedef short s16x8 __attribute__((ext_vector_type(8)));
typedef unsigned short u16;
typedef unsigned long long u64;

constexpr int Bb = 256, Tt = 128, Ff = 256, Hh = 512;
constexpr int TF = Tt * Ff;                       // 32768
constexpr long OFF_RECON = (long)Bb * Tt * Ff;    // 8388608
constexpr long OFF_H     = 2L * Bb * Tt * Ff;     // 16777216
constexpr long OFF_LOSS  = OFF_H + (long)Bb * Hh; // 16908288

__device__ inline float sigf(float v){ return 1.f / (1.f + expf(-v)); }
__device__ inline u16 f2b(float f){
  unsigned u = __float_as_uint(f);
  u += 0x7fffu + ((u >> 16) & 1u);   // RNE
  return (u16)(u >> 16);
}
__device__ inline float b2f(u16 b){ return __uint_as_float(((unsigned)b) << 16); }

__device__ inline f32x4 mfma16(bf16x8 a, bf16x8 b, f32x4 c){
  return __builtin_amdgcn_mfma_f32_16x16x32_bf16(a, b, c, 0, 0, 0);
}
__device__ inline bf16x8 ldb8(const u16* p){ return *reinterpret_cast<const bf16x8*>(p); }
__device__ inline bf16x8 cvt8(const float* p){
  const float4 a = ((const float4*)p)[0], b = ((const float4*)p)[1];
  s16x8 r;
  r[0]=f2b(a.x); r[1]=f2b(a.y); r[2]=f2b(a.z); r[3]=f2b(a.w);
  r[4]=f2b(b.x); r[5]=f2b(b.y); r[6]=f2b(b.z); r[7]=f2b(b.w);
  return __builtin_bit_cast(bf16x8, r);
}
// agent-coherent (L1-bypassing) 16B load of handoff data (hdec): 2x 8B relaxed atomics
__device__ inline bf16x8 ld_a8(const u16* p){
  u64 lo = __hip_atomic_load((const u64*)p,     __ATOMIC_RELAXED, __HIP_MEMORY_SCOPE_AGENT);
  u64 hi = __hip_atomic_load((const u64*)(p+4), __ATOMIC_RELAXED, __HIP_MEMORY_SCOPE_AGENT);
  union { u64 q[2]; bf16x8 v; } u; u.q[0]=lo; u.q[1]=hi; return u.v;
}

// ---------------- hoisted big GEMMs (gamma_h, beta for all t; [t][b][f] layout) ----------------
enum { M_GH, M_BETA };

struct P {
  const float *x, *mask, *deltas;
  const float *b_gh, *w_gx, *b_gx, *b_comb;
  const u16 *Wgh, *Wcomb;
  u16 *gammah, *beta;
};

template<int MODE>
__global__ __launch_bounds__(256) void gk(P p)
{
  constexpr int K = (MODE==M_GH) ? 256 : 512;
  const int lane = threadIdx.x & 63;
  const int w = threadIdx.x >> 6;
  const int m0 = blockIdx.y*64 + (w>>1)*32;
  const int n0 = blockIdx.x*64 + (w&1)*32;
  const int fr = lane & 15;
  const int kg = (lane >> 4) << 3;

  f32x4 acc[2][2] = {};
  for (int k = 0; k < K; k += 32) {
    const int kk = k + kg;
    bf16x8 a[2], b[2];
    #pragma unroll
    for (int r = 0; r < 2; ++r) {
      const int mr = m0 + 16*r + fr;
      if constexpr (MODE == M_GH) {
        a[r] = cvt8(p.deltas + (size_t)mr*256 + kk);
      } else {
        if (kk < 256) {
          const float4 d0 = *(const float4*)(p.deltas + (size_t)mr*256 + kk);
          const float4 d1 = *(const float4*)(p.deltas + (size_t)mr*256 + kk + 4);
          const float4 w0 = *(const float4*)(p.w_gx + kk);
          const float4 w1 = *(const float4*)(p.w_gx + kk + 4);
          const float4 g0 = *(const float4*)(p.b_gx + kk);
          const float4 g1 = *(const float4*)(p.b_gx + kk + 4);
          s16x8 v;
          v[0]=f2b(expf(-fmaxf(d0.x*w0.x+g0.x,0.f)));
          v[1]=f2b(expf(-fmaxf(d0.y*w0.y+g0.y,0.f)));
          v[2]=f2b(expf(-fmaxf(d0.z*w0.z+g0.z,0.f)));
          v[3]=f2b(expf(-fmaxf(d0.w*w0.w+g0.w,0.f)));
          v[4]=f2b(expf(-fmaxf(d1.x*w1.x+g1.x,0.f)));
          v[5]=f2b(expf(-fmaxf(d1.y*w1.y+g1.y,0.f)));
          v[6]=f2b(expf(-fmaxf(d1.z*w1.z+g1.z,0.f)));
          v[7]=f2b(expf(-fmaxf(d1.w*w1.w+g1.w,0.f)));
          a[r] = __builtin_bit_cast(bf16x8, v);
        } else {
          a[r] = cvt8(p.mask + (size_t)mr*256 + (kk-256));
        }
      }
    }
    #pragma unroll
    for (int cc = 0; cc < 2; ++cc) {
      const int nr = n0 + 16*cc + fr;
      if constexpr (MODE == M_GH) b[cc] = ldb8(p.Wgh   + (size_t)nr*256 + kk);
      else                        b[cc] = ldb8(p.Wcomb + (size_t)nr*512 + kk);
    }
    #pragma unroll
    for (int r = 0; r < 2; ++r)
      #pragma unroll
      for (int cc = 0; cc < 2; ++cc)
        acc[r][cc] = mfma16(a[r], b[cc], acc[r][cc]);
  }

  #pragma unroll
  for (int r = 0; r < 2; ++r)
    #pragma unroll
    for (int cc = 0; cc < 2; ++cc)
      #pragma unroll
      for (int q = 0; q < 4; ++q) {
        const int m = m0 + 16*r + (lane>>4)*4 + q;   // m = b*128 + t
        const int n = n0 + 16*cc + (lane&15);
        const size_t tb = (size_t)(m & 127)*256 + (m >> 7);   // [t][b]
        if constexpr (MODE == M_GH) {
          float v = expf(-fmaxf(acc[r][cc][q] + p.b_gh[n], 0.f));
          p.gammah[tb*512 + n] = f2b(v);
        } else {
          float v = sigf(acc[r][cc][q] + p.b_comb[n]);
          p.beta[tb*256 + n] = f2b(v);
        }
      }
}

// ---------------- weight conversion / den / final ----------------
constexpr int CV_TOT = 131072+131072+65536+131072+1048576+1048576; // 2554944
__global__ __launch_bounds__(256) void k_conv(
    const float* Wgh, const float* Whist, const float* Wfr, const float* Wcomb,
    const float* Wih, const float* Whh,
    u16* ogh, u16* ohist, u16* ofr, u16* ocomb, u16* oih, u16* ohh)
{
  int i = blockIdx.x*256 + threadIdx.x;
  if (i >= CV_TOT) return;
  int j = i;
  if (j < 131072) { ogh[j] = f2b(Wgh[j]); return; }       j -= 131072;
  if (j < 131072) { ohist[j] = f2b(Whist[j]); return; }   j -= 131072;
  if (j < 65536)  { ofr[j] = ((j>>8)==(j&255)) ? (u16)0 : f2b(Wfr[j]); return; } j -= 65536;
  if (j < 131072) { ocomb[j] = f2b(Wcomb[j]); return; }   j -= 131072;
  if (j < 1048576){ oih[j] = f2b(Wih[j]); return; }       j -= 1048576;
  ohh[j] = f2b(Whh[j]);
}

__global__ __launch_bounds__(256) void k_den(const float* __restrict__ mask, float* den)
{
  const int t = blockIdx.x;
  float s = 0.f;
  for (int b = 0; b < Bb; ++b)
    s += mask[(size_t)b*TF + (size_t)t*256 + threadIdx.x];
  __shared__ float red[4];
  #pragma unroll
  for (int o = 32; o; o >>= 1) s += __shfl_down(s, o);
  if ((threadIdx.x & 63) == 0) red[threadIdx.x >> 6] = s;
  __syncthreads();
  if (threadIdx.x == 0) den[t] = red[0]+red[1]+red[2]+red[3];
}

__global__ void k_final(const float* num, const float* den, float* out)
{
  if (threadIdx.x < 64) {
    int t = threadIdx.x;
    float s = num[t]/(den[t]+1e-12f) + num[t+64]/(den[t+64]+1e-12f);
    #pragma unroll
    for (int o = 32; o; o >>= 1) s += __shfl_down(s, o);
    if (t == 0) { out[OFF_LOSS] = s; out[OFF_LOSS+1] = 0.f; }
  }
}

// ---------------- recurrence: 8 slabs x 4-block groups, no grid barrier ----------------
struct PP {
  const float *x, *mask;
  const float *b_hist, *b_fr, *b_ih, *b_hh;
  const u16 *Whist, *Wfr, *Wih, *Whh, *gammah, *beta;
  u16 *hdec0, *hdec1;
  float *num, *out;
  unsigned *flags; int *xcc; unsigned *ctr;
};

// group = bid&7 (same residue mod 8 -> likely same XCD); member gj = bid>>3 owns
// h-cols [gj*128,(gj+1)*128) and output f-cols [gj*64,(gj+1)*64).
__global__ __launch_bounds__(512, 2) void k_loop(PP p)
{
  __shared__ char smem[84480];
  u16*   ximp_s = (u16*)smem;             // [32][264] bf16
  u16*   xr_s   = (u16*)(smem + 16896);   // [32][264] bf16 (aliases pre_s)
  float* pre_s  = (float*)(smem + 16896); // [8][16][132] f32
  __shared__ int s_fast;

  const int tid = threadIdx.x, lane = tid & 63, w = tid >> 6;
  const int fr = lane & 15, kg = (lane >> 4) << 3;
  const int bid = blockIdx.x;
  const int grp = bid & 7, gj = bid >> 3;
  const int m0 = grp * 32;

  // one-time: publish XCC id, global rendezvous, decide fast (same-XCD) sync path
  if (tid == 0) {
    unsigned xv;
    asm volatile("s_getreg_b32 %0, hwreg(HW_REG_XCC_ID)" : "=s"(xv));
    __hip_atomic_store(p.xcc + bid, (int)(xv & 15u), __ATOMIC_RELAXED, __HIP_MEMORY_SCOPE_AGENT);
    __hip_atomic_fetch_add(p.ctr, 1u, __ATOMIC_ACQ_REL, __HIP_MEMORY_SCOPE_AGENT);
    unsigned spin = 0;
    while (__hip_atomic_load(p.ctr, __ATOMIC_ACQUIRE, __HIP_MEMORY_SCOPE_AGENT) < 32u
           && spin < (1u<<20)) { __builtin_amdgcn_s_sleep(16); ++spin; }
    int x0 = __hip_atomic_load(p.xcc + grp,      __ATOMIC_RELAXED, __HIP_MEMORY_SCOPE_AGENT);
    int x1 = __hip_atomic_load(p.xcc + grp + 8,  __ATOMIC_RELAXED, __HIP_MEMORY_SCOPE_AGENT);
    int x2 = __hip_atomic_load(p.xcc + grp + 16, __ATOMIC_RELAXED, __HIP_MEMORY_SCOPE_AGENT);
    int x3 = __hip_atomic_load(p.xcc + grp + 24, __ATOMIC_RELAXED, __HIP_MEMORY_SCOPE_AGENT);
    s_fast = (x0 == x1) && (x1 == x2) && (x2 == x3);
  }
  __syncthreads();
  const int fast = s_fast;

  const int rh = w >> 2, cq = w & 3;    // phase A: row-half, col-quarter(64)
  const int gA = w & 3, rhB = w >> 2;   // phase B: gate, row-half
  const int lrow = tid >> 4;            // LSTM row 0..31
  const int lcol = (tid & 15) * 8;      // LSTM col base in member's 128-chunk

  const u16* hr = p.hdec0;
  u16* hw = p.hdec1;
  float c_reg[8];
  #pragma unroll
  for (int j = 0; j < 8; ++j) c_reg[j] = 0.f;

  for (int t = 0; t < Tt; ++t) {
    // ===== phase A: XH (K=512) -> xr(LDS) -> XU (K=256) -> outputs/ximp =====
    f32x4 acc[4] = {};
    for (int k = 0; k < 512; k += 32) {
      const int kk = k + kg;
      bf16x8 a = ld_a8(hr + (size_t)(m0 + rh*16 + fr)*512 + kk);
      #pragma unroll
      for (int cc = 0; cc < 4; ++cc) {
        bf16x8 b = ldb8(p.Whist + (size_t)(cq*64 + cc*16 + fr)*512 + kk);
        acc[cc] = mfma16(a, b, acc[cc]);
      }
    }
    float xhv[16];
    #pragma unroll
    for (int cc = 0; cc < 4; ++cc)
      #pragma unroll
      for (int q = 0; q < 4; ++q) {
        const int mi = rh*16 + (lane>>4)*4 + q;
        const int n  = cq*64 + cc*16 + fr;
        const float v = acc[cc][q] + p.b_hist[n];
        xhv[cc*4+q] = v;
        const size_t gi = (size_t)(m0+mi)*TF + (size_t)t*256 + n;
        const float mm = p.mask[gi];
        xr_s[mi*264 + n] = f2b(mm*p.x[gi] + (1.f-mm)*v);
      }
    __syncthreads();

    f32x4 acc2[4] = {};
    for (int k = 0; k < 256; k += 32) {
      const int kk = k + kg;
      bf16x8 a = *(const bf16x8*)(xr_s + (rh*16 + fr)*264 + kk);
      #pragma unroll
      for (int cc = 0; cc < 4; ++cc) {
        bf16x8 b = ldb8(p.Wfr + (size_t)(cq*64 + cc*16 + fr)*256 + kk);
        acc2[cc] = mfma16(a, b, acc2[cc]);
      }
    }
    float lnum = 0.f;
    #pragma unroll
    for (int cc = 0; cc < 4; ++cc)
      #pragma unroll
      for (int q = 0; q < 4; ++q) {
        const int mi = rh*16 + (lane>>4)*4 + q;
        const int n  = cq*64 + cc*16 + fr;
        const int m  = m0 + mi;
        const float xu  = acc2[cc][q] + p.b_fr[n];
        const float bet = b2f(p.beta[((size_t)t*256 + m)*256 + n]);
        const float xc  = bet*xu + (1.f-bet)*xhv[cc*4+q];
        const size_t gi = (size_t)m*TF + (size_t)t*256 + n;
        const float mm = p.mask[gi], xx = p.x[gi];
        const float xi = mm*xx + (1.f-mm)*xc;
        ximp_s[mi*264 + n] = f2b(xi);
        if (cq == gj) {
          p.out[OFF_RECON + gi] = xc;
          p.out[gi] = xi;
          lnum += fabsf(xc - xx)*mm;
        }
      }
    if (cq == gj) {
      #pragma unroll
      for (int o = 32; o; o >>= 1) lnum += __shfl_down(lnum, o);
      if (lane == 0) atomicAdd(p.num + t, lnum);
    }
    __syncthreads();

    // ===== phase B: gates (K=1024) n-split by member, fused LSTM =====
    f32x4 accg[8] = {};
    for (int k = 0; k < 1024; k += 32) {
      const int kk = k + kg;
      bf16x8 a;
      if (k < 256)      a = *(const bf16x8*)(ximp_s + (rhB*16 + fr)*264 + kk);
      else if (k < 512) a = cvt8(p.mask + (size_t)(m0 + rhB*16 + fr)*TF + (size_t)t*256 + (kk-256));
      else              a = ld_a8(hr + (size_t)(m0 + rhB*16 + fr)*512 + (kk-512));
      const u16* W = (k < 512) ? p.Wih : p.Whh;
      const int ko = (k < 512) ? kk : kk - 512;
      #pragma unroll
      for (int cc = 0; cc < 8; ++cc) {
        bf16x8 b = ldb8(W + (size_t)(gA*512 + gj*128 + cc*16 + fr)*512 + ko);
        accg[cc] = mfma16(a, b, accg[cc]);
      }
    }
    #pragma unroll
    for (int cc = 0; cc < 8; ++cc)
      #pragma unroll
      for (int q = 0; q < 4; ++q) {
        const int mi2 = (lane>>4)*4 + q;
        const int n2  = cc*16 + fr;
        pre_s[w*2112 + mi2*132 + n2] = accg[cc][q];
      }
    __syncthreads();
    {
      const int rh3 = lrow >> 4, mi2 = lrow & 15;
      s16x8 hv8;
      #pragma unroll
      for (int j = 0; j < 8; ++j) {
        const int col = lcol + j;
        const int ng  = gj*128 + col;
        const float pi = pre_s[(rh3*4+0)*2112 + mi2*132 + col] + p.b_ih[       ng] + p.b_hh[       ng];
        const float pf = pre_s[(rh3*4+1)*2112 + mi2*132 + col] + p.b_ih[ 512 + ng] + p.b_hh[ 512 + ng];
        const float pg = pre_s[(rh3*4+2)*2112 + mi2*132 + col] + p.b_ih[1024 + ng] + p.b_hh[1024 + ng];
        const float po = pre_s[(rh3*4+3)*2112 + mi2*132 + col] + p.b_ih[1536 + ng] + p.b_hh[1536 + ng];
        const float ig = sigf(pi), fg = sigf(pf);
        const float gg = tanhf(pg), og = sigf(po);
        const float cv = fg*c_reg[j] + ig*gg;
        c_reg[j] = cv;
        const float hv = og*tanhf(cv);
        if (t == Tt-1) {
          p.out[OFF_H + (size_t)(m0+lrow)*512 + ng] = hv;
        } else {
          const float gn = b2f(p.gammah[((size_t)(t+1)*256 + m0 + lrow)*512 + ng]);
          hv8[j] = (short)f2b(hv*gn);
        }
      }
      if (t < Tt-1)
        *(s16x8*)(hw + (size_t)(m0+lrow)*512 + gj*128 + lcol) = hv8;
    }
    if (t == Tt-1) break;

    // ===== step-end sync: 4-party flag barrier (hdec handoff) =====
    asm volatile("s_waitcnt vmcnt(0)" ::: "memory");  // this wave's stores in L2
    __syncthreads();                                   // all waves done
    if (w == 0 && lane < 4) {
      const unsigned tgt = (unsigned)(t + 1);
      unsigned* myf  = p.flags + bid*16;
      unsigned* memf = p.flags + (grp + 8*lane)*16;
      unsigned spin = 0;
      if (fast) {
        if (lane == 0) __hip_atomic_store(myf, tgt, __ATOMIC_RELAXED, __HIP_MEMORY_SCOPE_AGENT);
        while (__hip_atomic_load(memf, __ATOMIC_RELAXED, __HIP_MEMORY_SCOPE_AGENT) < tgt
               && spin < (1u<<20)) { __builtin_amdgcn_s_sleep(8); ++spin; }
      } else {
        if (lane == 0) __hip_atomic_store(myf, tgt, __ATOMIC_RELEASE, __HIP_MEMORY_SCOPE_AGENT);
        while (__hip_atomic_load(memf, __ATOMIC_ACQUIRE, __HIP_MEMORY_SCOPE_AGENT) < tgt
               && spin < (1u<<20)) { __builtin_amdgcn_s_sleep(8); ++spin; }
      }
    }
    __syncthreads();
    { u16* t2 = hw; hw = (u16*)hr; hr = t2; }
  }
}

extern "C" void kernel_launch(void* const* d_in, const int* in_sizes, int n_in,
                              void* d_out, int out_size, void* d_ws, size_t ws_size,
                              hipStream_t stream)
{
  char* wsb = (char*)d_ws;
  unsigned* flags = (unsigned*)(wsb + 0);        //  2048 (32 x 64B)
  int*      xcc   = (int*)(wsb + 2048);          //   128
  unsigned* ctr   = (unsigned*)(wsb + 2176);     //     4
  float*    num   = (float*)(wsb + 2240);        //   512
  float*    den   = (float*)(wsb + 2752);        //   512
  u16*  hdec0  = (u16*)(wsb + 4096);             //   262144
  u16*  hdec1  = (u16*)(wsb + 266240);           //   262144
  u16*  beta   = (u16*)(wsb + 528384);           // 16777216  [t][b][f]
  u16*  gammah = (u16*)(wsb + 17305600);         // 33554432  [t][b][h]
  u16*  Whist  = (u16*)(wsb + 50860032);         //   262144
  u16*  Wfr    = (u16*)(wsb + 51122176);         //   131072
  u16*  Wih    = (u16*)(wsb + 51253248);         //  2097152
  u16*  Whh    = (u16*)(wsb + 53350400);         //  2097152
  u16*  Wgh    = (u16*)(wsb + 55447552);         //   262144
  u16*  Wcomb  = (u16*)(wsb + 55709696);         //   262144 -> 55971840 total

  // zero flags/xcc/ctr/num/den + hdec0 on every (graph-replayed) call
  hipMemsetAsync(d_ws, 0, 266240, stream);

  k_conv<<<dim3((CV_TOT+255)/256), dim3(256), 0, stream>>>(
      (const float*)d_in[3], (const float*)d_in[7], (const float*)d_in[9],
      (const float*)d_in[11], (const float*)d_in[13], (const float*)d_in[15],
      Wgh, Whist, Wfr, Wcomb, Wih, Whh);
  k_den<<<dim3(128), dim3(256), 0, stream>>>((const float*)d_in[1], den);

  P p{};
  p.x = (const float*)d_in[0];  p.mask = (const float*)d_in[1];
  p.deltas = (const float*)d_in[2];
  p.b_gh = (const float*)d_in[4];  p.w_gx = (const float*)d_in[5];
  p.b_gx = (const float*)d_in[6];  p.b_comb = (const float*)d_in[12];
  p.Wgh = Wgh; p.Wcomb = Wcomb;
  p.gammah = gammah; p.beta = beta;
  gk<M_GH><<<dim3(8, 512), dim3(256), 0, stream>>>(p);    // gamma_h, all t
  gk<M_BETA><<<dim3(4, 512), dim3(256), 0, stream>>>(p);  // beta, all t

  PP q{};
  q.x = (const float*)d_in[0];  q.mask = (const float*)d_in[1];
  q.b_hist = (const float*)d_in[8];  q.b_fr = (const float*)d_in[10];
  q.b_ih = (const float*)d_in[14];   q.b_hh = (const float*)d_in[16];
  q.Whist = Whist; q.Wfr = Wfr; q.Wih = Wih; q.Whh = Whh;
  q.gammah = gammah; q.beta = beta;
  q.hdec0 = hdec0; q.hdec1 = hdec1;
  q.num = num; q.out = (float*)d_out;
  q.flags = flags; q.xcc = xcc; q.ctr = ctr;
  k_loop<<<dim3(32), dim3(512), 0, stream>>>(q);

  k_final<<<dim3(1), dim3(64), 0, stream>>>(num, den, (float*)d_out);
}

// Round 6
// 11296.109 us; speedup vs baseline: 1.6442x; 1.6442x over previous
//
#include <hip/hip_runtime.h>
#include <hip/hip_bf16.h>

typedef float f32x4 __attribute__((ext_vector_type(4)));
typedef __bf16 bf16x8 __attribute__((ext_vector_type(8)));
typedef short s16x8 __attribute__((ext_vector_type(8)));
typedef unsigned short u16;
typedef unsigned long long u64;
typedef unsigned char u8;

constexpr int Bb = 256, Tt = 128, Ff = 256, Hh = 512;
constexpr int TF = Tt * Ff;                       // 32768
constexpr long OFF_RECON = (long)Bb * Tt * Ff;    // 8388608
constexpr long OFF_H     = 2L * Bb * Tt * Ff;     // 16777216
constexpr long OFF_LOSS  = OFF_H + (long)Bb * Hh; // 16908288

__device__ inline float sigf(float v){ return 1.f / (1.f + expf(-v)); }
__device__ inline u16 f2b(float f){
  unsigned u = __float_as_uint(f);
  u += 0x7fffu + ((u >> 16) & 1u);   // RNE
  return (u16)(u >> 16);
}
__device__ inline float b2f(u16 b){ return __uint_as_float(((unsigned)b) << 16); }

// ---- fp8 e4m3 (OCP) conversion ----
__device__ inline unsigned f2e4_sw(float f){
  unsigned u = __float_as_uint(f);
  unsigned s = (u >> 24) & 0x80u;
  int e = (int)((u >> 23) & 0xff) - 127;
  unsigned m = u & 0x7fffffu;
  if (((u >> 23) & 0xff) == 0xff) return s | 0x7e;   // inf/nan -> sat
  if (e > 8 || (e == 8 && m > 0x600000)) return s | 0x7e; // > 448 sat
  if (e < -10) return s;
  if (e >= -6) {
    unsigned keep = m >> 20, rest = m & 0xfffffu;
    keep += (rest > 0x80000u) || (rest == 0x80000u && (keep & 1));
    unsigned ee = (unsigned)(e + 7);
    if (keep == 8) { keep = 0; ee += 1; }
    if (ee >= 16) return s | 0x7e;
    return s | (ee << 3) | keep;
  }
  unsigned full = (1u << 23) | m;
  int shift = 20 + (-6 - e);                 // 21..24
  unsigned keep = full >> shift;
  unsigned rest = full & ((1u << shift) - 1u);
  unsigned half = 1u << (shift - 1);
  keep += (rest > half) || (rest == half && (keep & 1));
  return s | keep;                            // keep==8 -> 0x08 == 2^-6 (correct)
}
__device__ inline unsigned f2e4(float f){
#if __has_builtin(__builtin_amdgcn_cvt_pk_fp8_f32)
  return (unsigned)__builtin_amdgcn_cvt_pk_fp8_f32(f, f, 0, false) & 0xffu;
#else
  return f2e4_sw(f);
#endif
}
__device__ inline unsigned pk2e4(float a, float b){
#if __has_builtin(__builtin_amdgcn_cvt_pk_fp8_f32)
  return (unsigned)__builtin_amdgcn_cvt_pk_fp8_f32(a, b, 0, false) & 0xffffu;
#else
  return f2e4_sw(a) | (f2e4_sw(b) << 8);
#endif
}
__device__ inline unsigned pk4e4(float a, float b, float c, float d){
#if __has_builtin(__builtin_amdgcn_cvt_pk_fp8_f32)
  int lo = __builtin_amdgcn_cvt_pk_fp8_f32(a, b, 0, false);
  return (unsigned)__builtin_amdgcn_cvt_pk_fp8_f32(c, d, lo & 0xffff, true);
#else
  return f2e4_sw(a) | (f2e4_sw(b)<<8) | (f2e4_sw(c)<<16) | (f2e4_sw(d)<<24);
#endif
}

__device__ inline f32x4 mfma16(bf16x8 a, bf16x8 b, f32x4 c){
  return __builtin_amdgcn_mfma_f32_16x16x32_bf16(a, b, c, 0, 0, 0);
}
__device__ inline f32x4 mfma8(u64 a, u64 b, f32x4 c){
  return __builtin_amdgcn_mfma_f32_16x16x32_fp8_fp8((long)a, (long)b, c, 0, 0, 0);
}
__device__ inline bf16x8 ldb8(const u16* p){ return *reinterpret_cast<const bf16x8*>(p); }
__device__ inline bf16x8 cvt8(const float* p){
  const float4 a = ((const float4*)p)[0], b = ((const float4*)p)[1];
  s16x8 r;
  r[0]=f2b(a.x); r[1]=f2b(a.y); r[2]=f2b(a.z); r[3]=f2b(a.w);
  r[4]=f2b(b.x); r[5]=f2b(b.y); r[6]=f2b(b.z); r[7]=f2b(b.w);
  return __builtin_bit_cast(bf16x8, r);
}
// L1-bypassing (agent-coherent) loads for cross-block handoff data
__device__ inline bf16x8 ld_a8(const u16* p){
  u64 lo = __hip_atomic_load((const u64*)p,     __ATOMIC_RELAXED, __HIP_MEMORY_SCOPE_AGENT);
  u64 hi = __hip_atomic_load((const u64*)(p+4), __ATOMIC_RELAXED, __HIP_MEMORY_SCOPE_AGENT);
  union { u64 q[2]; bf16x8 v; } u; u.q[0]=lo; u.q[1]=hi; return u.v;
}
__device__ inline u64 ld_a1(const u8* p){
  return __hip_atomic_load((const u64*)p, __ATOMIC_RELAXED, __HIP_MEMORY_SCOPE_AGENT);
}

// ---------------- hoisted big GEMMs (gamma_h, beta for all t; [t][b] layout) ----------------
enum { M_GH, M_BETA };

struct P {
  const float *x, *mask, *deltas;
  const float *b_gh, *w_gx, *b_gx, *b_comb;
  const u16 *Wgh, *Wcomb;
  u16 *gammah, *beta;
};

template<int MODE>
__global__ __launch_bounds__(256) void gk(P p)
{
  constexpr int K = (MODE==M_GH) ? 256 : 512;
  const int lane = threadIdx.x & 63;
  const int w = threadIdx.x >> 6;
  const int m0 = blockIdx.y*64 + (w>>1)*32;
  const int n0 = blockIdx.x*64 + (w&1)*32;
  const int fr = lane & 15;
  const int kg = (lane >> 4) << 3;

  f32x4 acc[2][2] = {};
  for (int k = 0; k < K; k += 32) {
    const int kk = k + kg;
    bf16x8 a[2], b[2];
    #pragma unroll
    for (int r = 0; r < 2; ++r) {
      const int mr = m0 + 16*r + fr;
      if constexpr (MODE == M_GH) {
        a[r] = cvt8(p.deltas + (size_t)mr*256 + kk);
      } else {
        if (kk < 256) {
          const float4 d0 = *(const float4*)(p.deltas + (size_t)mr*256 + kk);
          const float4 d1 = *(const float4*)(p.deltas + (size_t)mr*256 + kk + 4);
          const float4 w0 = *(const float4*)(p.w_gx + kk);
          const float4 w1 = *(const float4*)(p.w_gx + kk + 4);
          const float4 g0 = *(const float4*)(p.b_gx + kk);
          const float4 g1 = *(const float4*)(p.b_gx + kk + 4);
          s16x8 v;
          v[0]=f2b(expf(-fmaxf(d0.x*w0.x+g0.x,0.f)));
          v[1]=f2b(expf(-fmaxf(d0.y*w0.y+g0.y,0.f)));
          v[2]=f2b(expf(-fmaxf(d0.z*w0.z+g0.z,0.f)));
          v[3]=f2b(expf(-fmaxf(d0.w*w0.w+g0.w,0.f)));
          v[4]=f2b(expf(-fmaxf(d1.x*w1.x+g1.x,0.f)));
          v[5]=f2b(expf(-fmaxf(d1.y*w1.y+g1.y,0.f)));
          v[6]=f2b(expf(-fmaxf(d1.z*w1.z+g1.z,0.f)));
          v[7]=f2b(expf(-fmaxf(d1.w*w1.w+g1.w,0.f)));
          a[r] = __builtin_bit_cast(bf16x8, v);
        } else {
          a[r] = cvt8(p.mask + (size_t)mr*256 + (kk-256));
        }
      }
    }
    #pragma unroll
    for (int cc = 0; cc < 2; ++cc) {
      const int nr = n0 + 16*cc + fr;
      if constexpr (MODE == M_GH) b[cc] = ldb8(p.Wgh   + (size_t)nr*256 + kk);
      else                        b[cc] = ldb8(p.Wcomb + (size_t)nr*512 + kk);
    }
    #pragma unroll
    for (int r = 0; r < 2; ++r)
      #pragma unroll
      for (int cc = 0; cc < 2; ++cc)
        acc[r][cc] = mfma16(a[r], b[cc], acc[r][cc]);
  }

  #pragma unroll
  for (int r = 0; r < 2; ++r)
    #pragma unroll
    for (int cc = 0; cc < 2; ++cc)
      #pragma unroll
      for (int q = 0; q < 4; ++q) {
        const int m = m0 + 16*r + (lane>>4)*4 + q;   // m = b*128 + t
        const int n = n0 + 16*cc + (lane&15);
        const size_t tb = (size_t)(m & 127)*256 + (m >> 7);   // [t][b]
        if constexpr (MODE == M_GH) {
          float v = expf(-fmaxf(acc[r][cc][q] + p.b_gh[n], 0.f));
          p.gammah[tb*512 + n] = f2b(v);
        } else {
          float v = sigf(acc[r][cc][q] + p.b_comb[n]);
          p.beta[tb*256 + n] = f2b(v);
        }
      }
}

// ---------------- weight conversion / den / final ----------------
constexpr int CV_TOT = 131072+131072+65536+131072; // bf16 ones
__global__ __launch_bounds__(256) void k_conv(
    const float* Wgh, const float* Whist, const float* Wfr, const float* Wcomb,
    u16* ogh, u16* ohist, u16* ofr, u16* ocomb)
{
  int i = blockIdx.x*256 + threadIdx.x;
  if (i >= CV_TOT) return;
  int j = i;
  if (j < 131072) { ogh[j] = f2b(Wgh[j]); return; }       j -= 131072;
  if (j < 131072) { ohist[j] = f2b(Whist[j]); return; }   j -= 131072;
  if (j < 65536)  { ofr[j] = ((j>>8)==(j&255)) ? (u16)0 : f2b(Wfr[j]); return; } j -= 65536;
  ocomb[j] = f2b(Wcomb[j]);
}

__global__ __launch_bounds__(256) void k_conv8(
    const float* Wih, const float* Whh, u8* oih, u8* ohh)
{
  int i = blockIdx.x*256 + threadIdx.x;   // pair index, total 1048576
  if (i < 524288) {
    ((u16*)oih)[i] = (u16)pk2e4(Wih[2*i], Wih[2*i+1]);
  } else {
    int j = i - 524288;
    ((u16*)ohh)[j] = (u16)pk2e4(Whh[2*j], Whh[2*j+1]);
  }
}

__global__ __launch_bounds__(256) void k_den(const float* __restrict__ mask,
                                             float* den, u8* mask8)
{
  const int t = blockIdx.x;
  const int f = threadIdx.x;
  float s = 0.f;
  for (int b = 0; b < Bb; ++b) {
    float mv = mask[(size_t)b*TF + (size_t)t*256 + f];
    s += mv;
    mask8[((size_t)t*256 + b)*256 + f] = (u8)f2e4(mv);
  }
  __shared__ float red[4];
  #pragma unroll
  for (int o = 32; o; o >>= 1) s += __shfl_down(s, o);
  if ((f & 63) == 0) red[f >> 6] = s;
  __syncthreads();
  if (f == 0) den[t] = red[0]+red[1]+red[2]+red[3];
}

__global__ void k_final(const float* num, const float* den, float* out)
{
  if (threadIdx.x < 64) {
    int t = threadIdx.x;
    float s = num[t]/(den[t]+1e-12f) + num[t+64]/(den[t+64]+1e-12f);
    #pragma unroll
    for (int o = 32; o; o >>= 1) s += __shfl_down(s, o);
    if (t == 0) { out[OFF_LOSS] = s; out[OFF_LOSS+1] = 0.f; }
  }
}

// ---------------- recurrence: 8 slabs x 8 same-XCD members ----------------
struct PP {
  const float *x, *mask;
  const float *b_hist, *b_fr, *b_ih, *b_hh;
  const u16 *Whist, *Wfr, *gammah, *beta;
  const u8 *Wih8, *Whh8, *mask8;
  u16 *hb0, *hb1;
  u8 *h80, *h81;
  float *num, *out;
  unsigned *flags; int *xcc; unsigned *ctr;
};

// slab grp = bid&7 (all 8 members on XCD grp via round-robin dispatch);
// member gj = bid>>3 owns h-cols [gj*64,(gj+1)*64). Per-XCD L2 weight
// footprint: Whist 256K + Wfr 128K + Wih8 1M + Whh8 1M = 2.4MB < 4MB.
__global__ __launch_bounds__(512, 1) void k_loop(PP p)
{
  __shared__ char smem[8704 + 34816];
  u8*    ximp_s = (u8*)smem;              // [32][272] fp8
  u16*   xr_s   = (u16*)(smem + 8704);    // [32][264] bf16 (aliases pre_s)
  float* pre_s  = (float*)(smem + 8704);  // [4][32][68] f32
  __shared__ int s_fast;

  const int tid = threadIdx.x, lane = tid & 63, w = tid >> 6;
  const int fr = lane & 15, kg = (lane >> 4) << 3;
  const int bid = blockIdx.x;
  const int grp = bid & 7, gj = bid >> 3;
  const int m0 = grp * 32;

  // one-time: publish XCC id, rendezvous, pick fast (same-XCD) sync path
  if (tid == 0) {
    unsigned xv;
    asm volatile("s_getreg_b32 %0, hwreg(HW_REG_XCC_ID)" : "=s"(xv));
    __hip_atomic_store(p.xcc + bid, (int)(xv & 15u), __ATOMIC_RELAXED, __HIP_MEMORY_SCOPE_AGENT);
    __hip_atomic_fetch_add(p.ctr, 1u, __ATOMIC_ACQ_REL, __HIP_MEMORY_SCOPE_AGENT);
    unsigned spin = 0;
    while (__hip_atomic_load(p.ctr, __ATOMIC_ACQUIRE, __HIP_MEMORY_SCOPE_AGENT) < 64u
           && spin < (1u<<20)) { __builtin_amdgcn_s_sleep(16); ++spin; }
    int x0 = __hip_atomic_load(p.xcc + grp, __ATOMIC_RELAXED, __HIP_MEMORY_SCOPE_AGENT);
    int ok = 1;
    #pragma unroll
    for (int j = 1; j < 8; ++j) {
      int xj = __hip_atomic_load(p.xcc + grp + 8*j, __ATOMIC_RELAXED, __HIP_MEMORY_SCOPE_AGENT);
      ok &= (xj == x0);
    }
    s_fast = ok;
  }
  __syncthreads();
  const int fast = s_fast;

  const int rh = w >> 2, cq = w & 3;      // phase A: row-half, col-quarter(64)
  const int gw = w & 3, rhB = w >> 2;     // phase B: gate, row-half
  const int lrow = tid >> 4;              // LSTM row 0..31
  const int lcb = (tid & 15) * 4;         // LSTM col base (4 cols) in member's 64

  const u16* hr = p.hb0;  u16* hw = p.hb1;
  const u8*  hr8 = p.h80; u8*  hw8 = p.h81;
  float c_reg[4] = {0.f, 0.f, 0.f, 0.f};

  for (int t = 0; t < Tt; ++t) {
    // ===== phase A (redundant per member): XH -> xr(LDS) -> XU -> outputs =====
    f32x4 acc[4] = {};
    for (int k = 0; k < 512; k += 32) {
      const int kk = k + kg;
      bf16x8 a = ld_a8(hr + (size_t)(m0 + rh*16 + fr)*512 + kk);
      #pragma unroll
      for (int cc = 0; cc < 4; ++cc) {
        bf16x8 b = ldb8(p.Whist + (size_t)(cq*64 + cc*16 + fr)*512 + kk);
        acc[cc] = mfma16(a, b, acc[cc]);
      }
    }
    float xhv[16];
    #pragma unroll
    for (int cc = 0; cc < 4; ++cc)
      #pragma unroll
      for (int q = 0; q < 4; ++q) {
        const int mi = rh*16 + (lane>>4)*4 + q;
        const int n  = cq*64 + cc*16 + fr;
        const float v = acc[cc][q] + p.b_hist[n];
        xhv[cc*4+q] = v;
        const size_t gi = (size_t)(m0+mi)*TF + (size_t)t*256 + n;
        const float mm = __builtin_nontemporal_load(p.mask + gi);
        const float xx = __builtin_nontemporal_load(p.x + gi);
        xr_s[mi*264 + n] = f2b(mm*xx + (1.f-mm)*v);
      }
    __syncthreads();

    f32x4 acc2[4] = {};
    for (int k = 0; k < 256; k += 32) {
      const int kk = k + kg;
      bf16x8 a = *(const bf16x8*)(xr_s + (rh*16 + fr)*264 + kk);
      #pragma unroll
      for (int cc = 0; cc < 4; ++cc) {
        bf16x8 b = ldb8(p.Wfr + (size_t)(cq*64 + cc*16 + fr)*256 + kk);
        acc2[cc] = mfma16(a, b, acc2[cc]);
      }
    }
    float lnum = 0.f;
    #pragma unroll
    for (int cc = 0; cc < 4; ++cc)
      #pragma unroll
      for (int q = 0; q < 4; ++q) {
        const int mi = rh*16 + (lane>>4)*4 + q;
        const int n  = cq*64 + cc*16 + fr;
        const int m  = m0 + mi;
        const float xu  = acc2[cc][q] + p.b_fr[n];
        const float bet = b2f(__builtin_nontemporal_load(p.beta + ((size_t)t*256 + m)*256 + n));
        const float xc  = bet*xu + (1.f-bet)*xhv[cc*4+q];
        const size_t gi = (size_t)m*TF + (size_t)t*256 + n;
        const float mm = __builtin_nontemporal_load(p.mask + gi);
        const float xx = __builtin_nontemporal_load(p.x + gi);
        const float xi = mm*xx + (1.f-mm)*xc;
        ximp_s[mi*272 + n] = (u8)f2e4(xi);
        if (cq == gj) {
          __builtin_nontemporal_store(xc, p.out + OFF_RECON + gi);
          __builtin_nontemporal_store(xi, p.out + gi);
          lnum += fabsf(xc - xx)*mm;
        }
      }
    if (cq == gj) {
      #pragma unroll
      for (int o = 32; o; o >>= 1) lnum += __shfl_down(lnum, o);
      if (lane == 0) atomicAdd(p.num + t, lnum);
    }
    __syncthreads();

    // ===== phase B: gates fp8 (K=1024), member owns 64 h-cols x 4 gates =====
    f32x4 ag[4] = {};
    for (int k = 0; k < 1024; k += 32) {
      const int kk = k + kg;
      u64 a;
      if (k < 256)      a = *(const u64*)(ximp_s + (size_t)(rhB*16 + fr)*272 + kk);
      else if (k < 512) a = *(const u64*)(p.mask8 + ((size_t)t*256 + m0 + rhB*16 + fr)*256 + (kk-256));
      else              a = ld_a1(hr8 + (size_t)(m0 + rhB*16 + fr)*512 + (kk-512));
      const u8* W8 = (k < 512) ? p.Wih8 : p.Whh8;
      const int ko = (k < 512) ? kk : kk - 512;
      #pragma unroll
      for (int cc = 0; cc < 4; ++cc) {
        u64 b = *(const u64*)(W8 + (size_t)(gw*512 + gj*64 + cc*16 + fr)*512 + ko);
        ag[cc] = mfma8(a, b, ag[cc]);
      }
    }
    #pragma unroll
    for (int cc = 0; cc < 4; ++cc)
      #pragma unroll
      for (int q = 0; q < 4; ++q) {
        const int row = rhB*16 + (lane>>4)*4 + q;
        const int col = cc*16 + fr;
        pre_s[(gw*32 + row)*68 + col] = ag[cc][q];
      }
    __syncthreads();

    // fused LSTM: thread owns (lrow, 4 cols at lcb) of member's 64 h-cols
    {
      const int nb = gj*64 + lcb;
      float hvv[4];
      #pragma unroll
      for (int j = 0; j < 4; ++j) {
        const int n = nb + j;
        const float pi = pre_s[(0*32 + lrow)*68 + lcb + j] + p.b_ih[       n] + p.b_hh[       n];
        const float pf = pre_s[(1*32 + lrow)*68 + lcb + j] + p.b_ih[ 512 + n] + p.b_hh[ 512 + n];
        const float pg = pre_s[(2*32 + lrow)*68 + lcb + j] + p.b_ih[1024 + n] + p.b_hh[1024 + n];
        const float po = pre_s[(3*32 + lrow)*68 + lcb + j] + p.b_ih[1536 + n] + p.b_hh[1536 + n];
        const float ig = sigf(pi), fg = sigf(pf);
        const float gg = tanhf(pg), og = sigf(po);
        const float cv = fg*c_reg[j] + ig*gg;
        c_reg[j] = cv;
        hvv[j] = og*tanhf(cv);
      }
      if (t == Tt-1) {
        #pragma unroll
        for (int j = 0; j < 4; ++j)
          __builtin_nontemporal_store(hvv[j], p.out + OFF_H + (size_t)(m0+lrow)*512 + nb + j);
      } else {
        float hd[4];
        #pragma unroll
        for (int j = 0; j < 4; ++j) {
          const float gn = b2f(__builtin_nontemporal_load(
              p.gammah + ((size_t)(t+1)*256 + m0 + lrow)*512 + nb + j));
          hd[j] = hvv[j]*gn;
        }
        union { u64 q; u16 h[4]; } pb;
        pb.h[0]=f2b(hd[0]); pb.h[1]=f2b(hd[1]); pb.h[2]=f2b(hd[2]); pb.h[3]=f2b(hd[3]);
        *(u64*)(hw + (size_t)(m0+lrow)*512 + nb) = pb.q;
        *(unsigned*)(hw8 + (size_t)(m0+lrow)*512 + nb) = pk4e4(hd[0], hd[1], hd[2], hd[3]);
      }
    }
    if (t == Tt-1) break;

    // ===== step-end sync: 8-party flag barrier (same-XCD fast path) =====
    asm volatile("s_waitcnt vmcnt(0)" ::: "memory");
    __syncthreads();
    if (w == 0 && lane < 8) {
      const unsigned tgt = (unsigned)(t + 1);
      unsigned* myf  = p.flags + bid*16;
      unsigned* memf = p.flags + (grp + 8*lane)*16;
      unsigned spin = 0;
      if (fast) {
        if (lane == 0) __hip_atomic_store(myf, tgt, __ATOMIC_RELAXED, __HIP_MEMORY_SCOPE_AGENT);
        while (__hip_atomic_load(memf, __ATOMIC_RELAXED, __HIP_MEMORY_SCOPE_AGENT) < tgt
               && spin < (1u<<22)) { __builtin_amdgcn_s_sleep(2); ++spin; }
      } else {
        if (lane == 0) __hip_atomic_store(myf, tgt, __ATOMIC_RELEASE, __HIP_MEMORY_SCOPE_AGENT);
        while (__hip_atomic_load(memf, __ATOMIC_ACQUIRE, __HIP_MEMORY_SCOPE_AGENT) < tgt
               && spin < (1u<<22)) { __builtin_amdgcn_s_sleep(2); ++spin; }
      }
    }
    __syncthreads();
    { u16* t2 = hw; hw = (u16*)hr; hr = t2; }
    { u8*  t3 = hw8; hw8 = (u8*)hr8; hr8 = t3; }
  }
}

extern "C" void kernel_launch(void* const* d_in, const int* in_sizes, int n_in,
                              void* d_out, int out_size, void* d_ws, size_t ws_size,
                              hipStream_t stream)
{
  char* wsb = (char*)d_ws;
  unsigned* flags = (unsigned*)(wsb + 0);        //  4096 (64 x 64B)
  int*      xcc   = (int*)(wsb + 4096);          //   256
  unsigned* ctr   = (unsigned*)(wsb + 4352);     //     4 (+pad)
  float*    num   = (float*)(wsb + 4416);        //   512
  float*    den   = (float*)(wsb + 4928);        //   512 (+pad to 8192)
  u16*  hb0   = (u16*)(wsb + 8192);              //   262144
  u16*  hb1   = (u16*)(wsb + 270336);            //   262144
  u8*   h80   = (u8*)(wsb + 532480);             //   131072
  u8*   h81   = (u8*)(wsb + 663552);             //   131072
  u8*   mask8 = (u8*)(wsb + 794624);             //  8388608  [t][b][f]
  u16*  beta  = (u16*)(wsb + 9183232);           // 16777216  [t][b][f]
  u16*  gammah= (u16*)(wsb + 25960448);          // 33554432  [t][b][h]
  u16*  Whist = (u16*)(wsb + 59514880);          //   262144
  u16*  Wfr   = (u16*)(wsb + 59777024);          //   131072
  u16*  Wgh   = (u16*)(wsb + 59908096);          //   262144
  u16*  Wcomb = (u16*)(wsb + 60170240);          //   262144
  u8*   Wih8  = (u8*)(wsb + 60432384);           //  1048576
  u8*   Whh8  = (u8*)(wsb + 61480960);           //  1048576  -> 62529536 total

  // zero flags/xcc/ctr/num/den + hdec buffers on every (graph-replayed) call
  hipMemsetAsync(d_ws, 0, 794624, stream);

  k_conv<<<dim3((CV_TOT+255)/256), dim3(256), 0, stream>>>(
      (const float*)d_in[3], (const float*)d_in[7], (const float*)d_in[9],
      (const float*)d_in[11], Wgh, Whist, Wfr, Wcomb);
  k_conv8<<<dim3(4096), dim3(256), 0, stream>>>(
      (const float*)d_in[13], (const float*)d_in[15], Wih8, Whh8);
  k_den<<<dim3(128), dim3(256), 0, stream>>>((const float*)d_in[1], den, mask8);

  P p{};
  p.x = (const float*)d_in[0];  p.mask = (const float*)d_in[1];
  p.deltas = (const float*)d_in[2];
  p.b_gh = (const float*)d_in[4];  p.w_gx = (const float*)d_in[5];
  p.b_gx = (const float*)d_in[6];  p.b_comb = (const float*)d_in[12];
  p.Wgh = Wgh; p.Wcomb = Wcomb;
  p.gammah = gammah; p.beta = beta;
  gk<M_GH><<<dim3(8, 512), dim3(256), 0, stream>>>(p);    // gamma_h, all t
  gk<M_BETA><<<dim3(4, 512), dim3(256), 0, stream>>>(p);  // beta, all t

  PP q{};
  q.x = (const float*)d_in[0];  q.mask = (const float*)d_in[1];
  q.b_hist = (const float*)d_in[8];  q.b_fr = (const float*)d_in[10];
  q.b_ih = (const float*)d_in[14];   q.b_hh = (const float*)d_in[16];
  q.Whist = Whist; q.Wfr = Wfr; q.gammah = gammah; q.beta = beta;
  q.Wih8 = Wih8; q.Whh8 = Whh8; q.mask8 = mask8;
  q.hb0 = hb0; q.hb1 = hb1; q.h80 = h80; q.h81 = h81;
  q.num = num; q.out = (float*)d_out;
  q.flags = flags; q.xcc = xcc; q.ctr = ctr;
  k_loop<<<dim3(64), dim3(512), 0, stream>>>(q);

  k_final<<<dim3(1), dim3(64), 0, stream>>>(num, den, (float*)d_out);
}